// Round 7
// baseline (7147.645 us; speedup 1.0000x reference)
//
#include <hip/hip_runtime.h>
#include <hip/hip_bf16.h>
#include <stdint.h>

// Problem constants (from reference)
#define S_WORDS 2048
#define LMAX    16
#define CE      256
#define WE      512
#define HDIM    1024
#define GC      1024   // 4*CE
#define GW      4096   // 4*HDIM
#define KW      768    // WE + CE
#define NWG     256    // persistent workgroups for word recurrence (1/CU)

// Workspace layout (bytes) — high-water 50,331,648 (48 MiB)
#define IN_GATES_OFF 0                       // 2048*4096 fp32 = 33554432
#define LAST_OFF     33554432                // 2048*256 fp32  =  2097152
#define WT2C_OFF     35651584                // 256*1024 float2 = 2097152 (char weights)
#define WT2W_OFF     37748736                // 384*4096 float2 = 12582912
// Ring aliases WT2c (dead after char_lstm; memset enqueued after char_lstm):
#define RING_OFF     WT2C_OFF                // 4 slots * 1024 u64 = 32768

typedef float f32x4 __attribute__((ext_vector_type(4)));

static __device__ __forceinline__ float sigm(float x) { return 1.0f / (1.0f + __expf(-x)); }
// fast tanh: (e^{2|x|}-1)/(e^{2|x|}+1) with sign restore; clamp avoids inf/inf
static __device__ __forceinline__ float tanh_fast(float x) {
    float ax = fminf(fabsf(x), 15.0f);
    float e  = __expf(2.0f * ax);
    float t  = (e - 1.0f) / (e + 1.0f);
    return copysignf(t, x);
}

// ---------- prep: transposed k-major float2 pairs for coalesced reads ----------
__global__ void prep_c_kernel(const float* __restrict__ Wih,
                              const float* __restrict__ Whh,
                              float2* __restrict__ WT2c) {
    int idx = blockIdx.x * blockDim.x + threadIdx.x;   // 256*1024
    if (idx >= 256 * GC) return;
    int kp = idx >> 10, row = idx & (GC - 1);
    int k = kp * 2;
    float2 v;
    if (k < CE) { v.x = Wih[row * CE + k];      v.y = Wih[row * CE + k + 1]; }
    else        { v.x = Whh[row * CE + k - CE]; v.y = Whh[row * CE + k - CE + 1]; }
    WT2c[idx] = v;
}

__global__ void prep_w_kernel(const float* __restrict__ Wih,
                              float2* __restrict__ WT2w) {
    int idx = blockIdx.x * blockDim.x + threadIdx.x;   // 384*4096
    if (idx >= 384 * GW) return;
    int kp = idx >> 12, row = idx & (GW - 1);
    float2 v;
    v.x = Wih[row * KW + 2 * kp];
    v.y = Wih[row * KW + 2 * kp + 1];
    WT2w[idx] = v;
}

// ---------- char LSTM: 256 blocks x 256 threads; block handles 8 words ----------
__global__ void __launch_bounds__(256) char_lstm_kernel(
    const int* __restrict__ char_idxs,        // [2048][16]
    const int* __restrict__ char_lens,        // [2048]
    const float* __restrict__ char_emb,       // [256][256]
    const float* __restrict__ bih,            // [1024]
    const float* __restrict__ bhh,            // [1024]
    const float2* __restrict__ WT2c,          // [256][1024] k-pairs
    float* __restrict__ last_out)             // [2048][256]
{
    __shared__ float xh[8][2 * CE];           // 16 KB
    const int j = threadIdx.x;
    const int wbase = blockIdx.x * 8;

    float bias[4];
    #pragma unroll
    for (int g = 0; g < 4; g++) bias[g] = bih[g * CE + j] + bhh[g * CE + j];

    int len[8];
    float c[8];
    #pragma unroll
    for (int w = 0; w < 8; w++) {
        c[w] = 0.0f;
        xh[w][CE + j] = 0.0f;                 // h_{-1} = 0
        len[w] = char_lens[wbase + w];
    }

    for (int t = 0; t < LMAX; t++) {
        #pragma unroll
        for (int w = 0; w < 8; w++) {
            int ci = char_idxs[(wbase + w) * LMAX + t];
            xh[w][j] = char_emb[ci * CE + j];
        }
        __syncthreads();

        float acc[4][8];
        #pragma unroll
        for (int g = 0; g < 4; g++)
            #pragma unroll
            for (int w = 0; w < 8; w++) acc[g][w] = 0.0f;

        for (int kp = 0; kp < CE; kp++) {     // 256 pairs over K=512
            float2 wv[4];
            #pragma unroll
            for (int g = 0; g < 4; g++) wv[g] = WT2c[kp * GC + g * CE + j];
            #pragma unroll
            for (int w = 0; w < 8; w++) {
                float2 xv = *(const float2*)&xh[w][2 * kp];
                #pragma unroll
                for (int g = 0; g < 4; g++)
                    acc[g][w] = fmaf(wv[g].y, xv.y, fmaf(wv[g].x, xv.x, acc[g][w]));
            }
        }
        __syncthreads();                      // all reads of xh done

        #pragma unroll
        for (int w = 0; w < 8; w++) {
            float iv = sigm(acc[0][w] + bias[0]);
            float fv = sigm(acc[1][w] + bias[1]);
            float gv = tanhf(acc[2][w] + bias[2]);
            float ov = sigm(acc[3][w] + bias[3]);
            c[w] = fv * c[w] + iv * gv;
            float h = ov * tanhf(c[w]);
            xh[w][CE + j] = h;
            if (t == len[w] - 1) last_out[(wbase + w) * CE + j] = h;
        }
    }
}

// ---------- word-LSTM input gates GEMM: in_gates = [we|last] @ Wih_w^T + bias ----------
__global__ void __launch_bounds__(256) wordin_kernel(
    const int* __restrict__ word_idxs,
    const float* __restrict__ word_emb,          // [50000][512]
    const float* __restrict__ last,              // [2048][256]
    const float2* __restrict__ WT2w,             // [384][4096] k-pairs
    const float* __restrict__ bih,               // [4096]
    const float* __restrict__ bhh,               // [4096]
    float* __restrict__ in_gates)                // [2048][4096]
{
    __shared__ float xh[8][KW];                  // 24 KB
    const int j = threadIdx.x;
    const int wbase = (blockIdx.x & 255) * 8;
    const int rb = blockIdx.x >> 8;              // 0..3

    for (int w = 0; w < 8; w++) {
        int wi = word_idxs[wbase + w];
        xh[w][j]        = word_emb[wi * WE + j];
        xh[w][CE + j]   = word_emb[wi * WE + CE + j];
        xh[w][WE + j]   = last[(wbase + w) * CE + j];
    }
    __syncthreads();

    float acc[4][8];
    #pragma unroll
    for (int g = 0; g < 4; g++)
        #pragma unroll
        for (int w = 0; w < 8; w++) acc[g][w] = 0.0f;

    for (int kp = 0; kp < KW / 2; kp++) {        // 384 pairs
        float2 wv[4];
        #pragma unroll
        for (int g = 0; g < 4; g++) wv[g] = WT2w[kp * GW + rb * GC + g * CE + j];
        #pragma unroll
        for (int w = 0; w < 8; w++) {
            float2 xv = *(const float2*)&xh[w][2 * kp];
            #pragma unroll
            for (int g = 0; g < 4; g++)
                acc[g][w] = fmaf(wv[g].y, xv.y, fmaf(wv[g].x, xv.x, acc[g][w]));
        }
    }

    #pragma unroll
    for (int g = 0; g < 4; g++) {
        int row = rb * GC + g * CE + j;
        float bias = bih[row] + bhh[row];
        #pragma unroll
        for (int w = 0; w < 8; w++)
            in_gates[(wbase + w) * GW + row] = acc[g][w] + bias;
    }
}

// ---------- persistent word-LSTM recurrence (v7) ----------
// 256 WGs x 512 thr (8 waves, 1 WG/CU). WG b owns units [4b,4b+4); wave v handles
// unit 4b+(v&3), k-half (v>>2): 32 weights/lane (8 f32x4), VGPR/AGPR-resident.
// Sync v7: publish h via relaxed agent atomic EXCHANGE (RMW executes at the MALL
// ALU -> line ALLOCATES in MALL; r6's plain atomic stores wrote through to HBM,
// putting a ~900cy HBM fill in every step's poll path — FETCH_SIZE 298 MB sig).
// Poll is software-pipelined: a second pair of tag loads stays in flight, the
// older pair is checked at vmcnt(2) -> detect quantum ~RTT/2.
// Ring: 4 slots (pow2 -> t&3 addressing, no magic-mul on the critical path).
__global__ void __launch_bounds__(512, 2) word_rnn_kernel(
    const float* __restrict__ Whh,            // [4096][1024]
    const float* __restrict__ in_gates,       // [2048][4096]
    unsigned long long* __restrict__ ring,    // [4][1024] tagged h (zeroed)
    float* __restrict__ out)                  // [2048][1024]
{
    const int tid   = threadIdx.x;
    const int v     = tid >> 6;               // wave id 0..7
    const int l     = tid & 63;               // lane
    const int ul    = v & 3;                  // local unit 0..3
    const int kappa = v >> 2;                 // k-half 0/1
    const int unit  = blockIdx.x * 4 + ul;

    __shared__ float hbb[2][HDIM];            // 8 KB, double-buffered h broadcast
    __shared__ float gex[2][4][4];            // [kappa][local unit][gate] partial sums

    // resident weights: w[g][i] = Whh[g*H+unit][kappa*512 + i*256 + l*4 .. +3]
    f32x4 w[4][2];
    #pragma unroll
    for (int g = 0; g < 4; g++)
        #pragma unroll
        for (int i = 0; i < 2; i++)
            w[g][i] = *(const f32x4*)(Whh + (size_t)(g * HDIM + unit) * HDIM
                                      + kappa * 512 + i * 256 + l * 4);
    // light pin: opaque def discourages re-load sinking; only 8 f32x4 -> no spill pressure
    #pragma unroll
    for (int g = 0; g < 4; g++)
        #pragma unroll
        for (int i = 0; i < 2; i++)
            asm volatile("" : "+v"(w[g][i]));

    float c_reg = 0.0f;                       // live in wave-0 lanes 0..3 only

    for (int t = 0; t < S_WORDS; t++) {
        // prefetch input-gate contributions (wave-0 lanes 0..3), off critical path
        float ing0 = 0.f, ing1 = 0.f, ing2 = 0.f, ing3 = 0.f;
        if (tid < 4) {
            const float* ig = in_gates + (size_t)t * GW + blockIdx.x * 4 + tid;
            ing0 = ig[0 * HDIM]; ing1 = ig[1 * HDIM];
            ing2 = ig[2 * HDIM]; ing3 = ig[3 * HDIM];
        }

        // pipelined distributed poll: wave v owns ring slice [v*128, v*128+128)
        const unsigned long long* slot = ring + (size_t)(t & 3) * HDIM + v * 128;
        unsigned long long a0, a1;
        {
            unsigned long long p0, p1, q0, q1;
            p0 = __hip_atomic_load(slot + l,      __ATOMIC_RELAXED, __HIP_MEMORY_SCOPE_AGENT);
            p1 = __hip_atomic_load(slot + 64 + l, __ATOMIC_RELAXED, __HIP_MEMORY_SCOPE_AGENT);
            for (;;) {
                // keep a younger pair in flight; check the older pair at vmcnt(2)
                q0 = __hip_atomic_load(slot + l,      __ATOMIC_RELAXED, __HIP_MEMORY_SCOPE_AGENT);
                q1 = __hip_atomic_load(slot + 64 + l, __ATOMIC_RELAXED, __HIP_MEMORY_SCOPE_AGENT);
                bool ok = ((unsigned)(p0 >> 32) == (unsigned)t) &&
                          ((unsigned)(p1 >> 32) == (unsigned)t);
                if (__all(ok)) { a0 = p0; a1 = p1; break; }
                p0 = q0; p1 = q1;
            }
        }
        {
            union { unsigned u32; float f; } c0, c1;
            c0.u32 = (unsigned)a0; c1.u32 = (unsigned)a1;
            hbb[t & 1][v * 128 + l]      = c0.f;
            hbb[t & 1][v * 128 + 64 + l] = c1.f;
        }
        __syncthreads();                      // barrier 1: h broadcast complete

        // partial gates over this wave's k-half: 32 FMA/lane
        float acc0 = 0.f, acc1 = 0.f, acc2 = 0.f, acc3 = 0.f;
        #pragma unroll
        for (int i = 0; i < 2; i++) {
            f32x4 hv = *(const f32x4*)&hbb[t & 1][kappa * 512 + i * 256 + l * 4];
            #pragma unroll
            for (int e = 0; e < 4; e++) {
                acc0 = fmaf(w[0][i][e], hv[e], acc0);
                acc1 = fmaf(w[1][i][e], hv[e], acc1);
                acc2 = fmaf(w[2][i][e], hv[e], acc2);
                acc3 = fmaf(w[3][i][e], hv[e], acc3);
            }
        }
        #pragma unroll
        for (int off = 32; off >= 1; off >>= 1) {
            acc0 += __shfl_xor(acc0, off, 64);
            acc1 += __shfl_xor(acc1, off, 64);
            acc2 += __shfl_xor(acc2, off, 64);
            acc3 += __shfl_xor(acc3, off, 64);
        }
        if (l == 0) {
            gex[kappa][ul][0] = acc0; gex[kappa][ul][1] = acc1;
            gex[kappa][ul][2] = acc2; gex[kappa][ul][3] = acc3;
        }
        __syncthreads();                      // barrier 2: partials exchanged

        if (tid < 4) {                        // wave-0 lane tid -> unit 4b+tid
            float gi = gex[0][tid][0] + gex[1][tid][0] + ing0;
            float gf = gex[0][tid][1] + gex[1][tid][1] + ing1;
            float gg = gex[0][tid][2] + gex[1][tid][2] + ing2;
            float go = gex[0][tid][3] + gex[1][tid][3] + ing3;
            float iv = sigm(gi);
            float fv = sigm(gf);
            float gv = tanh_fast(gg);
            float ov = sigm(go);
            c_reg = fv * c_reg + iv * gv;
            float h = ov * tanh_fast(c_reg);
            union { float f; unsigned u32; } cv; cv.f = h;
            unsigned long long pv =
                ((unsigned long long)(unsigned)(t + 1) << 32) | (unsigned long long)cv.u32;
            // publish FIRST (critical path) via RMW exchange -> MALL-allocating
            (void)__hip_atomic_exchange(ring + (size_t)((t + 1) & 3) * HDIM + blockIdx.x * 4 + tid,
                                        pv, __ATOMIC_RELAXED, __HIP_MEMORY_SCOPE_AGENT);
            out[(size_t)t * HDIM + blockIdx.x * 4 + tid] = h;  // row fully tiled by WGs
        }
        // no trailing barrier: next step writes the other hbb buffer; gex(t+1)
        // writes happen only after barrier 1 of t+1, which wave 0 reaches after
        // its gex reads here.
    }
}

extern "C" void kernel_launch(void* const* d_in, const int* in_sizes, int n_in,
                              void* d_out, int out_size, void* d_ws, size_t ws_size,
                              hipStream_t stream) {
    const int* word_idxs = (const int*)d_in[0];
    const int* char_idxs = (const int*)d_in[1];
    const int* char_lens = (const int*)d_in[2];
    const float* char_emb = (const float*)d_in[3];
    const float* word_emb = (const float*)d_in[4];
    const float* Wih_c = (const float*)d_in[5];
    const float* Whh_c = (const float*)d_in[6];
    const float* bih_c = (const float*)d_in[7];
    const float* bhh_c = (const float*)d_in[8];
    const float* Wih_w = (const float*)d_in[9];
    const float* Whh_w = (const float*)d_in[10];
    const float* bih_w = (const float*)d_in[11];
    const float* bhh_w = (const float*)d_in[12];

    char* ws = (char*)d_ws;
    float*  in_gates = (float*)(ws + IN_GATES_OFF);
    float*  last     = (float*)(ws + LAST_OFF);
    float2* WT2c     = (float2*)(ws + WT2C_OFF);
    float2* WT2w     = (float2*)(ws + WT2W_OFF);
    unsigned long long* ring = (unsigned long long*)(ws + RING_OFF);

    hipLaunchKernelGGL(prep_c_kernel, dim3(1024), dim3(256), 0, stream,
                       Wih_c, Whh_c, WT2c);
    hipLaunchKernelGGL(prep_w_kernel, dim3(6144), dim3(256), 0, stream,
                       Wih_w, WT2w);
    hipLaunchKernelGGL(char_lstm_kernel, dim3(256), dim3(256), 0, stream,
                       char_idxs, char_lens, char_emb, bih_c, bhh_c, WT2c, last);
    // ring aliases WT2c — zero it only after char_lstm has consumed the weights.
    // slot0 = {h=0, tag=0} (valid t=0 input); slots 1..3 tag=0 != expected t -> not ready
    hipMemsetAsync(ws + RING_OFF, 0, 4 * HDIM * sizeof(unsigned long long), stream);
    hipLaunchKernelGGL(wordin_kernel, dim3(1024), dim3(256), 0, stream,
                       word_idxs, word_emb, last, WT2w, bih_w, bhh_w, in_gates);
    hipLaunchKernelGGL(word_rnn_kernel, dim3(NWG), dim3(512), 0, stream,
                       Whh_w, in_gates, ring, (float*)d_out);
}